// Round 1
// baseline (11978.372 us; speedup 1.0000x reference)
//
#include <hip/hip_runtime.h>
#include <hip/hip_cooperative_groups.h>

namespace cg = cooperative_groups;

// Problem constants (T,B,D,H = 512,32,512,512; bidirectional)
#define TT   512
#define BB   32
#define HH   512
#define GG   2048      // 4H gate rows per direction
#define NBLK 128       // 2 dirs x 64 blocks; each block owns 32 gate rows (8 j x 4 gates)
#define NTHR 256       // 4 waves: 2x2 grid of 16x16 MFMA C-tiles

typedef __attribute__((ext_vector_type(8))) short short8;
typedef __attribute__((ext_vector_type(4))) float f32x4;

__device__ __forceinline__ ushort bf16_rne(float v) {
    unsigned u = __builtin_bit_cast(unsigned, v);
    unsigned r = u + 0x7FFFu + ((u >> 16) & 1u);
    return (ushort)(r >> 16);
}
__device__ __forceinline__ float bf16_to_f(ushort h) {
    unsigned u = ((unsigned)h) << 16;
    return __builtin_bit_cast(float, u);
}

// Prologue: split x (fp32) into bf16 hi/lo planes so the persistent kernel can
// MFMA against them with fp32-equivalent accuracy (split-3 product).
__global__ void split_x_kernel(const float* __restrict__ x,
                               ushort* __restrict__ xh, ushort* __restrict__ xl,
                               int n) {
    int i = blockIdx.x * blockDim.x + threadIdx.x;
    int stride = gridDim.x * blockDim.x;
    for (; i < n; i += stride) {
        float v = x[i];
        ushort h = bf16_rne(v);
        xh[i] = h;
        xl[i] = bf16_rne(v - bf16_to_f(h));
    }
}

// Persistent bidirectional LSTM. One block = (dir, 8 hidden units). W-slice
// (32 gate rows x K=1024 = [W_ih | W_hh]) lives in LDS as bf16 hi/lo for the
// whole kernel. Per step: stage [x[t] | h] (bf16 hi/lo) in K-chunks of 128,
// MFMA 16x16x32 split-3 into fp32 acc, epilogue computes c/h for the owned
// (b,j) slice, writes y and the h hi/lo broadcast buffer, grid-syncs.
__global__ void __launch_bounds__(NTHR, 1)
lstm_persist(const ushort* __restrict__ x_hi, const ushort* __restrict__ x_lo,
             const float* __restrict__ h0, const float* __restrict__ c0,
             const float* __restrict__ W_ih, const float* __restrict__ b_ih,
             const float* __restrict__ W_hh, const float* __restrict__ b_hh,
             ushort* __restrict__ h_buf, float* __restrict__ out) {
    // LDS: W hi (64K) + W lo (64K), xh chunk hi/lo (8K+8K), C scratch, bias.
    __shared__ __align__(16) char sW[131072];
    __shared__ __align__(16) char sX[16384];
    __shared__ float sC[32][33];   // +1 pad: epilogue reads down a column
    __shared__ float sBias[32];

    const int tid = threadIdx.x;
    const int bid = blockIdx.x;
    const int d   = bid >> 6;      // direction
    const int blk = bid & 63;
    const int j0  = blk * 8;       // first owned hidden index

    // ---- one-time: load + split W slice into swizzled LDS ----
    // LDS row r (0..31): gate quadrant q=r>>3 (i,f,g,o), local j = r&7.
    for (int idx = tid; idx < 32 * 1024; idx += NTHR) {
        int r = idx >> 10;
        int col = idx & 1023;
        int g = (r >> 3) * 512 + j0 + (r & 7);
        float v = (col < 512) ? W_ih[(d * GG + g) * 512 + col]
                              : W_hh[(d * GG + g) * 512 + (col - 512)];
        ushort hi = bf16_rne(v);
        ushort lo = bf16_rne(v - bf16_to_f(hi));
        int byte = (r * 2048 + col * 2) ^ ((r & 7) << 4);   // G4 xor-swizzle
        *(ushort*)(sW + byte)         = hi;
        *(ushort*)(sW + 65536 + byte) = lo;
    }
    if (tid < 32) {
        int g = (tid >> 3) * 512 + j0 + (tid & 7);
        sBias[tid] = b_ih[d * GG + g] + b_hh[d * GG + g];
    }

    // ---- per-thread owned state: (b, j) with b=tid&31, j=j0+(tid>>5) ----
    const int b_own  = tid & 31;
    const int jl_own = tid >> 5;
    const int j_own  = j0 + jl_own;
    float c_reg = c0[(d * BB + b_own) * HH + j_own];
    float h_reg = h0[(d * BB + b_own) * HH + j_own];
    {   // init h broadcast buffer, parity 0
        ushort hi = bf16_rne(h_reg);
        ushort lo = bf16_rne(h_reg - bf16_to_f(hi));
        h_buf[((0 * 2 + d) * 2 + 0) * 16384 + b_own * HH + j_own] = hi;
        h_buf[((0 * 2 + d) * 2 + 1) * 16384 + b_own * HH + j_own] = lo;
    }
    __syncthreads();
    cg::grid_group grid = cg::this_grid();
    grid.sync();

    // MFMA wave/lane mapping (16x16x32 bf16): A row = lane&15 in b-tile,
    // k = (lane>>4)*8 + e; B col = lane&15 in g-tile, same k.
    const int lane = tid & 63;
    const int wid  = tid >> 6;
    const int wb   = wid >> 1;          // b-tile (0..1)
    const int wg   = wid & 1;           // g-tile (0..1)
    const int lr   = lane & 15;
    const int lk   = (lane >> 4) * 8;

    // staging map: thread -> (row=tid>>3, 16-col segment tid&7)
    const int s_row = tid >> 3;
    const int s_seg = tid & 7;

    for (int step = 0; step < TT; ++step) {
        const int t_eff = (d == 0) ? step : (TT - 1 - step);
        const int p = step & 1;

        f32x4 acc0 = {0.f, 0.f, 0.f, 0.f};
        f32x4 acc1 = acc0, acc2 = acc0;

        for (int kc = 0; kc < 8; ++kc) {   // K=1024 in chunks of 128
            // stage xh chunk (hi+lo planes) into swizzled sX
            const ushort *srch, *srcl;
            if (kc < 4) {
                int base = (t_eff * BB + s_row) * 512 + kc * 128 + s_seg * 16;
                srch = x_hi + base;
                srcl = x_lo + base;
            } else {
                int off = s_row * HH + (kc - 4) * 128 + s_seg * 16;
                srch = h_buf + ((p * 2 + d) * 2 + 0) * 16384 + off;
                srcl = h_buf + ((p * 2 + d) * 2 + 1) * 16384 + off;
            }
            int lbyte = s_row * 256 + s_seg * 32;
            int lb0 = lbyte ^ ((s_row & 7) << 4);
            int lb1 = (lbyte + 16) ^ ((s_row & 7) << 4);
            *(uint4*)(sX + lb0)        = *(const uint4*)(srch);
            *(uint4*)(sX + lb1)        = *(const uint4*)(srch + 8);
            *(uint4*)(sX + 8192 + lb0) = *(const uint4*)(srcl);
            *(uint4*)(sX + 8192 + lb1) = *(const uint4*)(srcl + 8);
            __syncthreads();

            #pragma unroll
            for (int ks = 0; ks < 4; ++ks) {
                int arow = wb * 16 + lr;
                int abyte = (arow * 256 + (ks * 32 + lk) * 2) ^ ((arow & 7) << 4);
                short8 a_hi = *(const short8*)(sX + abyte);
                short8 a_lo = *(const short8*)(sX + 8192 + abyte);

                int brow = wg * 16 + lr;
                int bbyte = (brow * 2048 + (kc * 128 + ks * 32 + lk) * 2) ^ ((brow & 7) << 4);
                short8 b_hi = *(const short8*)(sW + bbyte);
                short8 b_lo = *(const short8*)(sW + 65536 + bbyte);

                // split-3: (hi+lo)x(hi+lo) minus lo*lo (negligible)
                acc0 = __builtin_amdgcn_mfma_f32_16x16x32_bf16(a_hi, b_hi, acc0, 0, 0, 0);
                acc1 = __builtin_amdgcn_mfma_f32_16x16x32_bf16(a_lo, b_hi, acc1, 0, 0, 0);
                acc2 = __builtin_amdgcn_mfma_f32_16x16x32_bf16(a_hi, b_lo, acc2, 0, 0, 0);
            }
            __syncthreads();
        }

        // C/D layout (m89-verified): col = lane&15, row = (lane>>4)*4 + r
        #pragma unroll
        for (int r = 0; r < 4; ++r)
            sC[wb * 16 + (lane >> 4) * 4 + r][wg * 16 + lr] =
                acc0[r] + acc1[r] + acc2[r];
        __syncthreads();

        // epilogue: owned (b, j); gate rows q*8 + jl in C columns
        float gi = sC[b_own][jl_own]      + sBias[jl_own];
        float gf = sC[b_own][8 + jl_own]  + sBias[8 + jl_own];
        float gg = sC[b_own][16 + jl_own] + sBias[16 + jl_own];
        float go = sC[b_own][24 + jl_own] + sBias[24 + jl_own];
        float ig = 1.f / (1.f + expf(-gi));
        float fg = 1.f / (1.f + expf(-gf));
        float gt = tanhf(gg);
        float og = 1.f / (1.f + expf(-go));
        c_reg = fg * c_reg + ig * gt;
        h_reg = og * tanhf(c_reg);

        out[(t_eff * BB + b_own) * 1024 + d * 512 + j_own] = h_reg;

        ushort hi = bf16_rne(h_reg);
        ushort lo = bf16_rne(h_reg - bf16_to_f(hi));
        int pn = p ^ 1;
        h_buf[((pn * 2 + d) * 2 + 0) * 16384 + b_own * HH + j_own] = hi;
        h_buf[((pn * 2 + d) * 2 + 1) * 16384 + b_own * HH + j_own] = lo;

        grid.sync();   // h_buf[pn] complete + visible before next step reads it
    }

    // finals: output layout = y[512,32,1024] ++ h_out[2,32,512] ++ c_out[2,32,512]
    out[16777216 +         (d * BB + b_own) * HH + j_own] = h_reg;
    out[16777216 + 32768 + (d * BB + b_own) * HH + j_own] = c_reg;
}

extern "C" void kernel_launch(void* const* d_in, const int* in_sizes, int n_in,
                              void* d_out, int out_size, void* d_ws, size_t ws_size,
                              hipStream_t stream) {
    const float* x    = (const float*)d_in[0];
    const float* h0   = (const float*)d_in[1];
    const float* c0   = (const float*)d_in[2];
    const float* W_ih = (const float*)d_in[3];
    const float* b_ih = (const float*)d_in[4];
    const float* W_hh = (const float*)d_in[5];
    const float* b_hh = (const float*)d_in[6];
    float* out = (float*)d_out;

    // workspace layout: x_hi | x_lo (bf16 planes of x) | h broadcast buffers
    ushort* x_hi  = (ushort*)d_ws;
    ushort* x_lo  = x_hi + (size_t)TT * BB * 512;
    ushort* h_buf = x_lo + (size_t)TT * BB * 512;   // 2 parity x 2 dir x 2 plane x 32x512

    int n = TT * BB * 512;
    split_x_kernel<<<2048, 256, 0, stream>>>(x, x_hi, x_lo, n);

    void* args[] = { &x_hi, &x_lo, &h0, &c0, &W_ih, &b_ih, &W_hh, &b_hh, &h_buf, &out };
    hipLaunchCooperativeKernel((void*)lstm_persist, dim3(NBLK), dim3(NTHR),
                               args, 0, stream);
}

// Round 2
// 7322.982 us; speedup vs baseline: 1.6357x; 1.6357x over previous
//
#include <hip/hip_runtime.h>

// Problem constants (T,B,D,H = 512,32,512,512; bidirectional)
#define TT    512
#define BB    32
#define HH    512
#define GG    2048     // 4H gate rows per direction
#define NBDIR 64       // blocks per direction (each owns 8 hidden units = 32 gate rows)
#define NBLK  (2 * NBDIR)
#define NTHR  256      // 4 waves: 2x2 grid of 16x16 MFMA C-tiles

typedef __attribute__((ext_vector_type(8))) short short8;
typedef __attribute__((ext_vector_type(4))) float f32x4;

#define SELH 0x05040100u   // v_perm: [u0.lo16 | u1.lo16]  (hi bf16 plane)
#define SELL 0x07060302u   // v_perm: [u0.hi16 | u1.hi16]  (lo bf16 plane)

__device__ __forceinline__ ushort bf16_rne(float v) {
    unsigned u = __builtin_bit_cast(unsigned, v);
    unsigned r = u + 0x7FFFu + ((u >> 16) & 1u);
    return (ushort)(r >> 16);
}
__device__ __forceinline__ float bf16_to_f(ushort h) {
    unsigned u = ((unsigned)h) << 16;
    return __builtin_bit_cast(float, u);
}

// Prologue: split x into bf16 hi/lo planes; also zero the barrier counters.
__global__ void split_x_kernel(const float* __restrict__ x,
                               ushort* __restrict__ xh, ushort* __restrict__ xl,
                               unsigned* __restrict__ cnt, int n) {
    if (blockIdx.x == 0 && threadIdx.x < 64) cnt[threadIdx.x] = 0u;
    int i = blockIdx.x * blockDim.x + threadIdx.x;
    int stride = gridDim.x * blockDim.x;
    for (; i < n; i += stride) {
        float v = x[i];
        ushort h = bf16_rne(v);
        xh[i] = h;
        xl[i] = bf16_rne(v - bf16_to_f(h));
    }
}

// Persistent bidirectional LSTM with per-direction custom barrier.
__global__ void __launch_bounds__(NTHR, 1)
lstm_persist(const ushort* __restrict__ x_hi, const ushort* __restrict__ x_lo,
             const float* __restrict__ h0, const float* __restrict__ c0,
             const float* __restrict__ W_ih, const float* __restrict__ b_ih,
             const float* __restrict__ W_hh, const float* __restrict__ b_hh,
             unsigned* __restrict__ h_buf, unsigned* __restrict__ cnt_base,
             float* __restrict__ out) {
    __shared__ __align__(16) char sW[131072];   // W slice, hi plane + lo plane
    __shared__ __align__(16) char sX[16384];    // one K=128 chunk of [x|h], hi+lo
    __shared__ float sC[32][33];
    __shared__ float sBias[32];

    const int tid = threadIdx.x;
    const int bid = blockIdx.x;
    const int d   = bid / NBDIR;
    const int blk = bid % NBDIR;
    const int j0  = blk * 8;
    unsigned* cnt = cnt_base + d * 32;          // 128 B apart per direction

    // ---- one-time: load + split W slice into swizzled LDS ----
    for (int idx = tid; idx < 32 * 1024; idx += NTHR) {
        int r = idx >> 10;
        int col = idx & 1023;
        int g = (r >> 3) * 512 + j0 + (r & 7);
        float v = (col < 512) ? W_ih[(d * GG + g) * 512 + col]
                              : W_hh[(d * GG + g) * 512 + (col - 512)];
        ushort hi = bf16_rne(v);
        ushort lo = bf16_rne(v - bf16_to_f(hi));
        int byte = (r * 2048 + col * 2) ^ ((r & 7) << 4);
        *(ushort*)(sW + byte)         = hi;
        *(ushort*)(sW + 65536 + byte) = lo;
    }
    if (tid < 32) {
        int g = (tid >> 3) * 512 + j0 + (tid & 7);
        sBias[tid] = b_ih[d * GG + g] + b_hh[d * GG + g];
    }

    // ---- per-thread owned state ----
    const int b_own  = tid & 31;
    const int jl_own = tid >> 5;
    const int j_own  = j0 + jl_own;
    float c_reg = c0[(d * BB + b_own) * HH + j_own];
    float h_reg = h0[(d * BB + b_own) * HH + j_own];
    {
        ushort hi = bf16_rne(h_reg);
        ushort lo = bf16_rne(h_reg - bf16_to_f(hi));
        h_buf[(0 * 2 + d) * 16384 + b_own * HH + j_own] = (unsigned)hi | ((unsigned)lo << 16);
    }

    // MFMA lane mapping
    const int lane = tid & 63;
    const int wid  = tid >> 6;
    const int wb   = wid >> 1;
    const int wg   = wid & 1;
    const int lr   = lane & 15;
    const int lk   = (lane >> 4) * 8;
    // staging map
    const int s_row = tid >> 3;
    const int s_seg = tid & 7;
    const int lb0 = (s_row * 256 + s_seg * 32) ^ ((s_row & 7) << 4);
    const int lb1 = (s_row * 256 + s_seg * 32 + 16) ^ ((s_row & 7) << 4);

    // x prefetch registers (one full step's x half, K=512)
    uint4 xrh[4][2], xrl[4][2];
    auto prefetch_x = [&](int t) {
        #pragma unroll
        for (int c = 0; c < 4; ++c) {
            const ushort* ph = x_hi + (t * BB + s_row) * 512 + c * 128 + s_seg * 16;
            const ushort* pl = x_lo + (t * BB + s_row) * 512 + c * 128 + s_seg * 16;
            xrh[c][0] = *(const uint4*)ph;
            xrh[c][1] = *(const uint4*)(ph + 8);
            xrl[c][0] = *(const uint4*)pl;
            xrl[c][1] = *(const uint4*)(pl + 8);
        }
    };

    // barrier pieces: arrive (release) / wait (acquire poll) — per direction
    auto arrive = [&]() {
        __syncthreads();   // drains this block's h_buf stores (vmcnt) before release
        if (tid == 0) {
            __builtin_amdgcn_fence(__ATOMIC_RELEASE, "agent");
            __hip_atomic_fetch_add(cnt, 1u, __ATOMIC_RELAXED, __HIP_MEMORY_SCOPE_AGENT);
        }
    };
    auto wait_for = [&](unsigned target) {
        if (tid == 0) {
            while (__hip_atomic_load(cnt, __ATOMIC_ACQUIRE, __HIP_MEMORY_SCOPE_AGENT) < target)
                __builtin_amdgcn_s_sleep(2);
        }
        __syncthreads();
    };

    auto mfma_chunk = [&](int kcg, f32x4& a0, f32x4& a1, f32x4& a2) {
        #pragma unroll
        for (int ks = 0; ks < 4; ++ks) {
            int arow = wb * 16 + lr;
            int abyte = (arow * 256 + (ks * 32 + lk) * 2) ^ ((arow & 7) << 4);
            short8 a_hi = *(const short8*)(sX + abyte);
            short8 a_lo = *(const short8*)(sX + 8192 + abyte);
            int brow = wg * 16 + lr;
            int bbyte = (brow * 2048 + (kcg * 128 + ks * 32 + lk) * 2) ^ ((brow & 7) << 4);
            short8 b_hi = *(const short8*)(sW + bbyte);
            short8 b_lo = *(const short8*)(sW + 65536 + bbyte);
            a0 = __builtin_amdgcn_mfma_f32_16x16x32_bf16(a_hi, b_hi, a0, 0, 0, 0);
            a1 = __builtin_amdgcn_mfma_f32_16x16x32_bf16(a_lo, b_hi, a1, 0, 0, 0);
            a2 = __builtin_amdgcn_mfma_f32_16x16x32_bf16(a_hi, b_lo, a2, 0, 0, 0);
        }
    };

    // init: prefetch x for step 0; barrier epoch 0 publishes h_buf parity 0
    prefetch_x(d ? (TT - 1) : 0);
    arrive();
    wait_for(NBDIR);

    for (int step = 0; step < TT; ++step) {
        const int t_eff = d ? (TT - 1 - step) : step;
        const int p = step & 1;

        // issue h loads early (packed hi|lo u32); latency hidden under x chunks
        uint4 hr[4][4];
        {
            const unsigned* hsrc = h_buf + (p * 2 + d) * 16384 + s_row * HH + s_seg * 16;
            #pragma unroll
            for (int c = 0; c < 4; ++c)
                #pragma unroll
                for (int q = 0; q < 4; ++q)
                    hr[c][q] = *(const uint4*)(hsrc + c * 128 + q * 4);
        }

        f32x4 acc0 = {0.f, 0.f, 0.f, 0.f};
        f32x4 acc1 = acc0, acc2 = acc0;

        // x chunks (K cols 0..511) from prefetched registers
        #pragma unroll
        for (int kc = 0; kc < 4; ++kc) {
            *(uint4*)(sX + lb0)        = xrh[kc][0];
            *(uint4*)(sX + lb1)        = xrh[kc][1];
            *(uint4*)(sX + 8192 + lb0) = xrl[kc][0];
            *(uint4*)(sX + 8192 + lb1) = xrl[kc][1];
            __syncthreads();
            mfma_chunk(kc, acc0, acc1, acc2);
            __syncthreads();
        }
        // h chunks (K cols 512..1023): unpack packed u32 -> hi/lo planes
        #pragma unroll
        for (int kc = 0; kc < 4; ++kc) {
            uint4 u0 = hr[kc][0], u1 = hr[kc][1], u2 = hr[kc][2], u3 = hr[kc][3];
            uint4 hA = { __builtin_amdgcn_perm(u0.y, u0.x, SELH), __builtin_amdgcn_perm(u0.w, u0.z, SELH),
                         __builtin_amdgcn_perm(u1.y, u1.x, SELH), __builtin_amdgcn_perm(u1.w, u1.z, SELH) };
            uint4 hB = { __builtin_amdgcn_perm(u2.y, u2.x, SELH), __builtin_amdgcn_perm(u2.w, u2.z, SELH),
                         __builtin_amdgcn_perm(u3.y, u3.x, SELH), __builtin_amdgcn_perm(u3.w, u3.z, SELH) };
            uint4 lA = { __builtin_amdgcn_perm(u0.y, u0.x, SELL), __builtin_amdgcn_perm(u0.w, u0.z, SELL),
                         __builtin_amdgcn_perm(u1.y, u1.x, SELL), __builtin_amdgcn_perm(u1.w, u1.z, SELL) };
            uint4 lB = { __builtin_amdgcn_perm(u2.y, u2.x, SELL), __builtin_amdgcn_perm(u2.w, u2.z, SELL),
                         __builtin_amdgcn_perm(u3.y, u3.x, SELL), __builtin_amdgcn_perm(u3.w, u3.z, SELL) };
            *(uint4*)(sX + lb0)        = hA;
            *(uint4*)(sX + lb1)        = hB;
            *(uint4*)(sX + 8192 + lb0) = lA;
            *(uint4*)(sX + 8192 + lb1) = lB;
            __syncthreads();
            mfma_chunk(kc + 4, acc0, acc1, acc2);
            __syncthreads();
        }

        // C/D layout: col = lane&15, row = (lane>>4)*4 + r
        #pragma unroll
        for (int r = 0; r < 4; ++r)
            sC[wb * 16 + (lane >> 4) * 4 + r][wg * 16 + lr] = acc0[r] + acc1[r] + acc2[r];
        __syncthreads();

        float gi = sC[b_own][jl_own]      + sBias[jl_own];
        float gf = sC[b_own][8 + jl_own]  + sBias[8 + jl_own];
        float gg = sC[b_own][16 + jl_own] + sBias[16 + jl_own];
        float go = sC[b_own][24 + jl_own] + sBias[24 + jl_own];
        float ig = 1.f / (1.f + expf(-gi));
        float fg = 1.f / (1.f + expf(-gf));
        float gt = tanhf(gg);
        float og = 1.f / (1.f + expf(-go));
        c_reg = fg * c_reg + ig * gt;
        h_reg = og * tanhf(c_reg);

        out[(t_eff * BB + b_own) * 1024 + d * 512 + j_own] = h_reg;
        {
            ushort hi = bf16_rne(h_reg);
            ushort lo = bf16_rne(h_reg - bf16_to_f(hi));
            h_buf[((p ^ 1) * 2 + d) * 16384 + b_own * HH + j_own] =
                (unsigned)hi | ((unsigned)lo << 16);
        }

        if (step + 1 < TT) {
            arrive();                             // release h(t) to peers
            prefetch_x(d ? (TT - 2 - step) : (step + 1));   // in flight during poll
            wait_for((unsigned)NBDIR * (step + 2));
        }
    }

    out[16777216 +         (d * BB + b_own) * HH + j_own] = h_reg;
    out[16777216 + 32768 + (d * BB + b_own) * HH + j_own] = c_reg;
}

extern "C" void kernel_launch(void* const* d_in, const int* in_sizes, int n_in,
                              void* d_out, int out_size, void* d_ws, size_t ws_size,
                              hipStream_t stream) {
    const float* x    = (const float*)d_in[0];
    const float* h0   = (const float*)d_in[1];
    const float* c0   = (const float*)d_in[2];
    const float* W_ih = (const float*)d_in[3];
    const float* b_ih = (const float*)d_in[4];
    const float* W_hh = (const float*)d_in[5];
    const float* b_hh = (const float*)d_in[6];
    float* out = (float*)d_out;

    // ws layout: x_hi | x_lo (bf16 planes) | h_buf (packed u32, 2 parity x 2 dir) | counters
    ushort*   x_hi  = (ushort*)d_ws;
    ushort*   x_lo  = x_hi + (size_t)TT * BB * 512;
    unsigned* h_buf = (unsigned*)(x_lo + (size_t)TT * BB * 512);
    unsigned* cnt   = h_buf + 4 * 16384;

    int n = TT * BB * 512;
    split_x_kernel<<<2048, 256, 0, stream>>>(x, x_hi, x_lo, cnt, n);

    void* args[] = { &x_hi, &x_lo, &h0, &c0, &W_ih, &b_ih, &W_hh, &b_hh, &h_buf, &cnt, &out };
    hipLaunchCooperativeKernel((void*)lstm_persist, dim3(NBLK), dim3(NTHR),
                               args, 0, stream);
}

// Round 3
// 3161.750 us; speedup vs baseline: 3.7885x; 2.3161x over previous
//
#include <hip/hip_runtime.h>

// Problem constants (T,B,D,H = 512,32,512,512; bidirectional)
#define TT    512
#define BB    32
#define HH    512
#define NBDIR 128          // blocks per direction; each owns 4 hidden units (16 gate rows)
#define NTHR_R 128         // recurrence block: 2 waves

typedef __attribute__((ext_vector_type(8))) short short8;
typedef __attribute__((ext_vector_type(4))) float f32x4;
typedef __attribute__((ext_vector_type(4))) unsigned u32x4;
typedef __attribute__((ext_vector_type(2))) unsigned u32x2;

#define SELH 0x05040100u   // v_perm: [src1.lo16 | src0.lo16] -> hi bf16 plane of 2 elems
#define SELL 0x07060302u   // lo plane

__device__ __forceinline__ ushort bf16_rne(float v) {
    unsigned u = __builtin_bit_cast(unsigned, v);
    unsigned r = u + 0x7FFFu + ((u >> 16) & 1u);
    return (ushort)(r >> 16);
}
__device__ __forceinline__ float bf16_to_f(ushort h) {
    unsigned u = ((unsigned)h) << 16;
    return __builtin_bit_cast(float, u);
}

// coherent (device-scope) 16B load: bypasses L1/L2, reads the mall. Caller
// manages vmcnt via the explicit ledger (asm waitcnt + sched_barrier).
__device__ __forceinline__ u32x4 ld_cohere_x4(const unsigned* p) {
    u32x4 r;
    asm volatile("global_load_dwordx4 %0, %1, off sc0 sc1" : "=v"(r) : "v"(p) : "memory");
    return r;
}
__device__ __forceinline__ unsigned ld_plain_x1(const unsigned* p) {
    unsigned r;
    asm volatile("global_load_dword %0, %1, off" : "=v"(r) : "v"(p) : "memory");
    return r;
}
#define WAIT_VM(N) do { asm volatile("s_waitcnt vmcnt(" #N ")" ::: "memory"); \
                        __builtin_amdgcn_sched_barrier(0); } while (0)

__device__ __forceinline__ void unpack8(const u32x4& A, const u32x4& B,
                                        short8& hi, short8& lo) {
    u32x4 h = { __builtin_amdgcn_perm(A[1], A[0], SELH), __builtin_amdgcn_perm(A[3], A[2], SELH),
                __builtin_amdgcn_perm(B[1], B[0], SELH), __builtin_amdgcn_perm(B[3], B[2], SELH) };
    u32x4 l = { __builtin_amdgcn_perm(A[1], A[0], SELL), __builtin_amdgcn_perm(A[3], A[2], SELL),
                __builtin_amdgcn_perm(B[1], B[0], SELL), __builtin_amdgcn_perm(B[3], B[2], SELL) };
    hi = __builtin_bit_cast(short8, h);
    lo = __builtin_bit_cast(short8, l);
}

// ---------------------------------------------------------------------------
// Pre-pass: XP[d][blk][t][b][gl] = bf16hi|lo<<16 of (x . W_ih[d]^T), gates in
// per-recurrence-block order gl = q*4+jl for gate g = q*512 + blk*4 + jl.
// Tiles: 128 M x 128 N, K=512 chunked by 64, split-3 bf16 MFMA, fp32 acc.
// Also zeroes the barrier flags (runs before the cooperative kernel).
// ---------------------------------------------------------------------------
__global__ void __launch_bounds__(256, 1)
xpre_gemm(const float* __restrict__ x, const float* __restrict__ W_ih,
          unsigned* __restrict__ XP, unsigned* __restrict__ flags) {
    __shared__ __align__(16) char sA[32768];   // [128 m][64 k] hi 16K + lo 16K, swizzled
    __shared__ __align__(16) char sB[32768];
    const int tid = threadIdx.x;
    const int bid = blockIdx.x;
    if (bid == 0) flags[tid] = 0u;             // 256 flags zeroed
    const int d  = bid & 1;
    const int nt = (bid >> 1) & 15;
    const int mt = bid >> 5;
    const int lane = tid & 63, wid = tid >> 6;
    const int wm = wid >> 1, wn = wid & 1;
    const int lr = lane & 15, lk8 = (lane >> 4) * 8;

    f32x4 acc[16];
    #pragma unroll
    for (int i = 0; i < 16; ++i) acc[i] = (f32x4){0.f, 0.f, 0.f, 0.f};

    const float* Ab = x + (size_t)(mt * 128) * 512;
    const float* Bb = W_ih + ((size_t)d * 2048 + nt * 128) * 512;

    for (int kc = 0; kc < 8; ++kc) {
        #pragma unroll
        for (int i = 0; i < 8; ++i) {
            int f = i * 256 + tid;             // 2048 float4 per matrix per chunk
            int row = f >> 4, fc = f & 15;
            int byte = (row * 128 + fc * 8) ^ ((row & 7) << 4);
            f32x4 va = *(const f32x4*)(Ab + (size_t)row * 512 + kc * 64 + fc * 4);
            f32x4 vb = *(const f32x4*)(Bb + (size_t)row * 512 + kc * 64 + fc * 4);
            ushort h0 = bf16_rne(va[0]), h1 = bf16_rne(va[1]), h2 = bf16_rne(va[2]), h3 = bf16_rne(va[3]);
            ushort l0 = bf16_rne(va[0] - bf16_to_f(h0)), l1 = bf16_rne(va[1] - bf16_to_f(h1));
            ushort l2 = bf16_rne(va[2] - bf16_to_f(h2)), l3 = bf16_rne(va[3] - bf16_to_f(h3));
            *(u32x2*)(sA + byte)         = (u32x2){ (unsigned)h0 | ((unsigned)h1 << 16),
                                                    (unsigned)h2 | ((unsigned)h3 << 16) };
            *(u32x2*)(sA + 16384 + byte) = (u32x2){ (unsigned)l0 | ((unsigned)l1 << 16),
                                                    (unsigned)l2 | ((unsigned)l3 << 16) };
            h0 = bf16_rne(vb[0]); h1 = bf16_rne(vb[1]); h2 = bf16_rne(vb[2]); h3 = bf16_rne(vb[3]);
            l0 = bf16_rne(vb[0] - bf16_to_f(h0)); l1 = bf16_rne(vb[1] - bf16_to_f(h1));
            l2 = bf16_rne(vb[2] - bf16_to_f(h2)); l3 = bf16_rne(vb[3] - bf16_to_f(h3));
            *(u32x2*)(sB + byte)         = (u32x2){ (unsigned)h0 | ((unsigned)h1 << 16),
                                                    (unsigned)h2 | ((unsigned)h3 << 16) };
            *(u32x2*)(sB + 16384 + byte) = (u32x2){ (unsigned)l0 | ((unsigned)l1 << 16),
                                                    (unsigned)l2 | ((unsigned)l3 << 16) };
        }
        __syncthreads();
        #pragma unroll
        for (int ks = 0; ks < 2; ++ks) {
            short8 bh[4], bl[4];
            #pragma unroll
            for (int ns = 0; ns < 4; ++ns) {
                int brow = wn * 64 + ns * 16 + lr;
                int byte = (brow * 128 + (ks * 32 + lk8) * 2) ^ ((brow & 7) << 4);
                bh[ns] = *(const short8*)(sB + byte);
                bl[ns] = *(const short8*)(sB + 16384 + byte);
            }
            #pragma unroll
            for (int ms = 0; ms < 4; ++ms) {
                int arow = wm * 64 + ms * 16 + lr;
                int byte = (arow * 128 + (ks * 32 + lk8) * 2) ^ ((arow & 7) << 4);
                short8 ah = *(const short8*)(sA + byte);
                short8 al = *(const short8*)(sA + 16384 + byte);
                #pragma unroll
                for (int ns = 0; ns < 4; ++ns) {
                    acc[ms*4+ns] = __builtin_amdgcn_mfma_f32_16x16x32_bf16(ah, bh[ns], acc[ms*4+ns], 0,0,0);
                    acc[ms*4+ns] = __builtin_amdgcn_mfma_f32_16x16x32_bf16(al, bh[ns], acc[ms*4+ns], 0,0,0);
                    acc[ms*4+ns] = __builtin_amdgcn_mfma_f32_16x16x32_bf16(ah, bl[ns], acc[ms*4+ns], 0,0,0);
                }
            }
        }
        __syncthreads();
    }
    // epilogue: pack + scatter into recurrence-blocked layout
    #pragma unroll
    for (int ms = 0; ms < 4; ++ms)
    #pragma unroll
    for (int ns = 0; ns < 4; ++ns)
    #pragma unroll
    for (int r = 0; r < 4; ++r) {
        float v = acc[ms*4+ns][r];
        int m = mt * 128 + wm * 64 + ms * 16 + (lane >> 4) * 4 + r;
        int n = nt * 128 + wn * 64 + ns * 16 + lr;
        int t = m >> 5, b = m & 31;
        int q = n >> 9, rem = n & 511, bk = rem >> 2, jl = rem & 3;
        ushort hi = bf16_rne(v);
        ushort lo = bf16_rne(v - bf16_to_f(hi));
        XP[((((size_t)d * 128 + bk) * 512 + t) * 32 + b) * 16 + (q * 4 + jl)] =
            (unsigned)hi | ((unsigned)lo << 16);
    }
}

// ---------------------------------------------------------------------------
// Persistent recurrence: 256 blocks (2 dir x 128), 128 threads (2 waves).
// Block owns 4 hidden units (16 gate rows); W_hh slice stationary in LDS
// (bf16 hi+lo, 32 KB). Per step: poll per-block flags (no fences), read h
// directly global->reg via sc0sc1 dwordx4 (vmcnt ledger), 48 MFMAs/wave into
// one f32x4 acc, epilogue adds XP slice + bias, activations, publish h+flag.
// ---------------------------------------------------------------------------
__global__ void __launch_bounds__(NTHR_R, 1)
lstm_persist(const float* __restrict__ h0, const float* __restrict__ c0,
             const float* __restrict__ W_hh, const float* __restrict__ b_ih,
             const float* __restrict__ b_hh, const unsigned* __restrict__ XP,
             unsigned* __restrict__ h_buf, unsigned* __restrict__ flags,
             float* __restrict__ out) {
    __shared__ __align__(16) char sW[32768];   // [16 gates][512 k] hi 16K + lo 16K, swizzled
    __shared__ float sC[32][17];
    __shared__ float sBias[16];

    const int tid = threadIdx.x, bid = blockIdx.x;
    const int d = bid >> 7, blk = bid & 127, j0 = blk * 4;

    for (int idx = tid; idx < 16 * 512; idx += NTHR_R) {
        int r = idx >> 9, col = idx & 511;
        int g = (r >> 2) * 512 + j0 + (r & 3);
        float v = W_hh[((size_t)d * 2048 + g) * 512 + col];
        ushort hi = bf16_rne(v), lo = bf16_rne(v - bf16_to_f(hi));
        int byte = (r * 1024 + col * 2) ^ ((r & 7) << 4);
        *(ushort*)(sW + byte)         = hi;
        *(ushort*)(sW + 16384 + byte) = lo;
    }
    if (tid < 16) {
        int g = (tid >> 2) * 512 + j0 + (tid & 3);
        sBias[tid] = b_ih[d * 2048 + g] + b_hh[d * 2048 + g];
    }

    const int b_own = tid >> 2, jl_own = tid & 3, j_own = j0 + jl_own;
    float c_reg = c0[(d * BB + b_own) * HH + j_own];
    float h_reg = h0[(d * BB + b_own) * HH + j_own];
    {
        ushort hi = bf16_rne(h_reg), lo = bf16_rne(h_reg - bf16_to_f(hi));
        __hip_atomic_store(h_buf + (0 * 2 + d) * 16384 + b_own * HH + j_own,
                           (unsigned)hi | ((unsigned)lo << 16),
                           __ATOMIC_RELAXED, __HIP_MEMORY_SCOPE_AGENT);
    }
    __syncthreads();   // drains vmcnt; sW/sBias ready
    if (tid == 0)
        __hip_atomic_store(flags + d * NBDIR + blk, 1u,
                           __ATOMIC_RELAXED, __HIP_MEMORY_SCOPE_AGENT);

    const int lane = tid & 63, w = tid >> 6;
    const int lr = lane & 15, lk8 = (lane >> 4) * 8;
    unsigned* fl = flags + d * NBDIR;

    for (int s = 0; s < TT; ++s) {
        const int t_eff = d ? (TT - 1 - s) : s;
        const int p = s & 1;

        // XP acc-init prefetch (cached; hidden under the poll)
        const unsigned* xpb = XP + (((size_t)d * 128 + blk) * 512 + t_eff) * 512;
        unsigned xr0 = ld_plain_x1(xpb + (w * 16 + (lane >> 4) * 4 + 0) * 16 + lr);
        unsigned xr1 = ld_plain_x1(xpb + (w * 16 + (lane >> 4) * 4 + 1) * 16 + lr);
        unsigned xr2 = ld_plain_x1(xpb + (w * 16 + (lane >> 4) * 4 + 2) * 16 + lr);
        unsigned xr3 = ld_plain_x1(xpb + (w * 16 + (lane >> 4) * 4 + 3) * 16 + lr);

        // barrier: wait until every peer block published state s
        if (tid < 64) {
            unsigned tgt = (unsigned)s + 1u;
            for (;;) {
                unsigned a = __hip_atomic_load(fl + tid,      __ATOMIC_RELAXED, __HIP_MEMORY_SCOPE_AGENT);
                unsigned b = __hip_atomic_load(fl + 64 + tid, __ATOMIC_RELAXED, __HIP_MEMORY_SCOPE_AGENT);
                if (__all(a >= tgt && b >= tgt)) break;
                __builtin_amdgcn_s_sleep(1);
            }
        }
        __syncthreads();
        WAIT_VM(0);    // ledger baseline: xp + poll loads fully retired

        // h ledger: wave w covers A-rows b = w*16 + lr; k = ks*32 + lk8
        const unsigned* hb = h_buf + (p * 2 + d) * 16384 + (w * 16 + lr) * HH;
        u32x4 A0[8], A1[8];
        f32x4 acc = {0.f, 0.f, 0.f, 0.f};

        auto issue_kb = [&](u32x4 (&buf)[8], int kb) {
            #pragma unroll
            for (int i = 0; i < 4; ++i) {
                const unsigned* pp = hb + kb * 128 + i * 32 + lk8;
                buf[2*i]   = ld_cohere_x4(pp);
                buf[2*i+1] = ld_cohere_x4(pp + 4);
            }
        };
        auto do_kb = [&](u32x4 (&buf)[8], int kb) {
            #pragma unroll
            for (int i = 0; i < 4; ++i) {
                short8 ah, al;
                unpack8(buf[2*i], buf[2*i+1], ah, al);
                int byte = (lr * 1024 + (kb * 128 + i * 32 + lk8) * 2) ^ ((lr & 7) << 4);
                short8 bh = *(const short8*)(sW + byte);
                short8 bl = *(const short8*)(sW + 16384 + byte);
                acc = __builtin_amdgcn_mfma_f32_16x16x32_bf16(ah, bh, acc, 0, 0, 0);
                acc = __builtin_amdgcn_mfma_f32_16x16x32_bf16(al, bh, acc, 0, 0, 0);
                acc = __builtin_amdgcn_mfma_f32_16x16x32_bf16(ah, bl, acc, 0, 0, 0);
            }
        };

        issue_kb(A0, 0);
        issue_kb(A1, 1);
        WAIT_VM(8);  do_kb(A0, 0);
        issue_kb(A0, 2);
        WAIT_VM(8);  do_kb(A1, 1);
        issue_kb(A1, 3);
        WAIT_VM(8);  do_kb(A0, 2);
        WAIT_VM(0);  do_kb(A1, 3);

        // epilogue: C(row=b, col=gl) + XP
        {
            float xf0 = bf16_to_f((ushort)(xr0 & 0xFFFF)) + bf16_to_f((ushort)(xr0 >> 16));
            float xf1 = bf16_to_f((ushort)(xr1 & 0xFFFF)) + bf16_to_f((ushort)(xr1 >> 16));
            float xf2 = bf16_to_f((ushort)(xr2 & 0xFFFF)) + bf16_to_f((ushort)(xr2 >> 16));
            float xf3 = bf16_to_f((ushort)(xr3 & 0xFFFF)) + bf16_to_f((ushort)(xr3 >> 16));
            int row = w * 16 + (lane >> 4) * 4;
            sC[row + 0][lr] = acc[0] + xf0;
            sC[row + 1][lr] = acc[1] + xf1;
            sC[row + 2][lr] = acc[2] + xf2;
            sC[row + 3][lr] = acc[3] + xf3;
        }
        __syncthreads();

        float gi = sC[b_own][ 0 + jl_own] + sBias[ 0 + jl_own];
        float gf = sC[b_own][ 4 + jl_own] + sBias[ 4 + jl_own];
        float gg = sC[b_own][ 8 + jl_own] + sBias[ 8 + jl_own];
        float go = sC[b_own][12 + jl_own] + sBias[12 + jl_own];
        float ig = 1.f / (1.f + expf(-gi));
        float fg = 1.f / (1.f + expf(-gf));
        float gt = tanhf(gg);
        float og = 1.f / (1.f + expf(-go));
        c_reg = fg * c_reg + ig * gt;
        h_reg = og * tanhf(c_reg);

        out[(t_eff * BB + b_own) * 1024 + d * 512 + j_own] = h_reg;
        {
            ushort hi = bf16_rne(h_reg), lo = bf16_rne(h_reg - bf16_to_f(hi));
            __hip_atomic_store(h_buf + ((p ^ 1) * 2 + d) * 16384 + b_own * HH + j_own,
                               (unsigned)hi | ((unsigned)lo << 16),
                               __ATOMIC_RELAXED, __HIP_MEMORY_SCOPE_AGENT);
        }
        __syncthreads();   // drains this wave's stores (vmcnt) before flag
        if (tid == 0)
            __hip_atomic_store(flags + d * NBDIR + blk, (unsigned)s + 2u,
                               __ATOMIC_RELAXED, __HIP_MEMORY_SCOPE_AGENT);
    }

    out[16777216 +         (d * BB + b_own) * HH + j_own] = h_reg;
    out[16777216 + 32768 + (d * BB + b_own) * HH + j_own] = c_reg;
}

extern "C" void kernel_launch(void* const* d_in, const int* in_sizes, int n_in,
                              void* d_out, int out_size, void* d_ws, size_t ws_size,
                              hipStream_t stream) {
    const float* x    = (const float*)d_in[0];
    const float* h0   = (const float*)d_in[1];
    const float* c0   = (const float*)d_in[2];
    const float* W_ih = (const float*)d_in[3];
    const float* b_ih = (const float*)d_in[4];
    const float* W_hh = (const float*)d_in[5];
    const float* b_hh = (const float*)d_in[6];
    float* out = (float*)d_out;

    // ws: XP (2*128*512*32*16 u32 = 128 MiB) | h_buf (64K u32) | flags (256 u32)
    unsigned* XP    = (unsigned*)d_ws;
    unsigned* h_buf = XP + (size_t)2 * 128 * 512 * 32 * 16;
    unsigned* flags = h_buf + 4 * 16384;

    xpre_gemm<<<4096, 256, 0, stream>>>(x, W_ih, XP, flags);

    void* args[] = { &h0, &c0, &W_hh, &b_ih, &b_hh, &XP, &h_buf, &flags, &out };
    hipLaunchCooperativeKernel((void*)lstm_persist, dim3(2 * NBDIR), dim3(NTHR_R),
                               args, 0, stream);
}